// Round 1
// 259.268 us; speedup vs baseline: 1.0735x; 1.0735x over previous
//
#include <hip/hip_runtime.h>
#include <hip/hip_bf16.h>

// Problem constants: N=100000 nodes, E=1200000 edges, D=64, K=3 hops.
#define GN 100000
#define GE 1200000
#define GD 64
#define NG 256                 // col groups
#define CPG 391                // cols per group (256*391 = 100096 >= GN)
#define CAP 6144               // bucket capacity per group (mean 4688, std 68)

// ws_size ~256 MB (observed). This layout uses ~51 MB.
//
// History (see git log): r11 radix-partition CSR build; r12 predicated
// 16-edge gather blocks (45.7 us/hop, FETCH 73 MB); r13 REGRESSION: a
// runtime-branch row loader was if-converted -> both loads issued ->
// FETCH doubled. Lesson: no runtime dtype branches in hot loops.
// r14 = r12 gather + p1+init fusion. r15 (this): dinv-PRESCALE — all
// propagation buffers store dinv[c]*x so the hop loop is an unweighted
// gather-sum (no per-edge dinv[r] loads: 12->8 VMEM/iter, ~16 fewer
// random lines/node); csr holds byte offsets (r<<7) for 1-add X
// addressing; p2 seeds Xs=bf16(dinv*w); p1init writes OUT only.

// ---------------------------------------------------------------------------
// Runtime dtype detection. flags[0]=1 if weight/alpha bf16 else fp32.
// flags[1]=1 if edge_index int64 else int32.  Also zeroes gcount.
// ---------------------------------------------------------------------------
__global__ void detect_kernel(const void* __restrict__ w,
                              const void* __restrict__ edge,
                              int* __restrict__ flags, int* __restrict__ gcount) {
    __shared__ int s_badw, s_edgenz;
    if (threadIdx.x == 0) { s_badw = 0; s_edgenz = 0; }
    gcount[threadIdx.x] = 0;
    __syncthreads();
    const unsigned short* wh = (const unsigned short*)w;
    const unsigned int*   ei = (const unsigned int*)edge;
    int badw = 0, edgenz = 0;
    for (int i = threadIdx.x; i < 4096; i += 256) {
        unsigned int bits = ((unsigned int)wh[i]) << 16;
        float v = __uint_as_float(bits);
        if (!(fabsf(v) <= 100.0f)) badw = 1;         // NaN/Inf/huge -> fp32 backing
        if ((i & 1) == 1 && ei[i] != 0u) edgenz = 1; // odd word nonzero -> int32
    }
    if (badw)   atomicOr(&s_badw, 1);
    if (edgenz) atomicOr(&s_edgenz, 1);
    __syncthreads();
    if (threadIdx.x == 0) {
        flags[0] = s_badw ? 0 : 1;
        flags[1] = s_edgenz ? 0 : 1;
    }
}

__device__ __forceinline__ int ld_row(const int* __restrict__ edge, int e, int e64) {
    return e64 ? edge[2 * (size_t)e] : edge[e];
}
__device__ __forceinline__ int ld_col(const int* __restrict__ edge, int e, int e64) {
    return e64 ? edge[2 * ((size_t)GE + (size_t)e)] : edge[(size_t)GE + (size_t)e];
}
__device__ __forceinline__ float ld_f(const void* __restrict__ p, size_t i, int bf16f) {
    if (bf16f) return __bfloat162float(((const __hip_bfloat16*)p)[i]);
    return ((const float*)p)[i];
}

__device__ __forceinline__ float bf_lo(unsigned u) { return __uint_as_float(u << 16); }
__device__ __forceinline__ float bf_hi(unsigned u) { return __uint_as_float(u & 0xFFFF0000u); }
__device__ __forceinline__ unsigned bf16bits(float f) {
    __hip_bfloat16 h = __float2bfloat16(f);
    unsigned short s;
    __builtin_memcpy(&s, &h, 2);
    return (unsigned)s;
}

// ---- fused P1 (blocks 0..NG-1) + OUT-init (remaining blocks) ----
// P1: partition edges into NG col-group buckets (packed (c_local<<17)|r).
// init: OUT = bf16(alpha[0] * weight). (X seeding moved to p2: Xs=dinv*w.)
__global__ void p1init_kernel(const int* __restrict__ edge, const int* __restrict__ flags,
                              int* __restrict__ gcount, unsigned* __restrict__ bucket,
                              int E, int chunk,
                              const void* __restrict__ w, const void* __restrict__ alpha,
                              __hip_bfloat16* __restrict__ OUT, int nd) {
    if (blockIdx.x < NG) {
        __shared__ int cnt[NG];
        __shared__ int base[NG];
        int t = threadIdx.x;
        int e64 = flags[1];
        cnt[t] = 0;
        __syncthreads();
        int lo = blockIdx.x * chunk;
        int hiE = min(lo + chunk, E);
        // pass A: count valid edges per group
        for (int e = lo + t; e < hiE; e += 256) {
            int c = ld_col(edge, e, e64);
            int r = ld_row(edge, e, e64);
            if ((unsigned)c < (unsigned)GN && (unsigned)r < (unsigned)GN)
                atomicAdd(&cnt[c / CPG], 1);
        }
        __syncthreads();
        int cv = cnt[t];
        base[t] = (cv > 0) ? atomicAdd(&gcount[t], cv) : 0;
        __syncthreads();
        cnt[t] = 0;   // reuse as running offsets
        __syncthreads();
        // pass B: write entries (chunk is L2-hot from pass A)
        for (int e = lo + t; e < hiE; e += 256) {
            int c = ld_col(edge, e, e64);
            int r = ld_row(edge, e, e64);
            if ((unsigned)c < (unsigned)GN && (unsigned)r < (unsigned)GN) {
                int g = c / CPG;
                int idx = base[g] + atomicAdd(&cnt[g], 1);
                if (idx < CAP)
                    bucket[(size_t)g * CAP + idx] = ((unsigned)(c - g * CPG) << 17) | (unsigned)r;
            }
        }
    } else {
        int bid = blockIdx.x - NG;
        int i = 4 * (bid * 256 + (int)threadIdx.x);
        int wbf = flags[0];
        if (i < nd) {
            float a0 = ld_f(alpha, 0, wbf);
            float v0 = ld_f(w, i + 0, wbf);
            float v1 = ld_f(w, i + 1, wbf);
            float v2 = ld_f(w, i + 2, wbf);
            float v3 = ld_f(w, i + 3, wbf);
            uint2 oq;
            oq.x = (bf16bits(a0 * v1) << 16) | bf16bits(a0 * v0);
            oq.y = (bf16bits(a0 * v3) << 16) | bf16bits(a0 * v2);
            *(uint2*)(OUT + i) = oq;
        }
    }
}

// ---- P2: per group, self-scan gcount -> base; LDS hist -> dinv + rowptr +
// csr (byte offsets r<<7) + Xs = bf16(dinv * weight) seeding. ----
__global__ void p2_kernel(const unsigned* __restrict__ bucket, const int* __restrict__ gcount,
                          int* __restrict__ rowptr, float* __restrict__ dinv,
                          int* __restrict__ csr,
                          const void* __restrict__ w, const int* __restrict__ flags,
                          __hip_bfloat16* __restrict__ XS) {
    int g = blockIdx.x;
    int t = threadIdx.x;
    __shared__ int gs[NG];
    __shared__ int hist[512];
    __shared__ int s[512];
    __shared__ float sdv[512];
    int gv = gcount[t]; if (gv > CAP) gv = CAP;
    gs[t] = gv;
    hist[t] = 0; hist[t + 256] = 0;
    __syncthreads();
    for (int off = 1; off < NG; off <<= 1) {
        int u = (t >= off) ? gs[t - off] : 0;
        __syncthreads();
        gs[t] += u;
        __syncthreads();
    }
    int mg = gcount[g]; if (mg > CAP) mg = CAP;
    int gb = gs[g] - mg;          // exclusive group base
    int m = mg;
    const unsigned* bk = bucket + (size_t)g * CAP;
    for (int idx = t; idx < m; idx += 256)
        atomicAdd(&hist[bk[idx] >> 17], 1);
    __syncthreads();
    int h0 = hist[t], h1 = hist[t + 256];
    s[t] = h0; s[t + 256] = h1;
    __syncthreads();
    for (int off = 1; off < 512; off <<= 1) {
        int v0 = (t >= off) ? s[t - off] : 0;
        int v1 = (t + 256 >= off) ? s[t + 256 - off] : 0;
        __syncthreads();
        s[t] += v0; s[t + 256] += v1;
        __syncthreads();
    }
    // s = inclusive scan; rowptr[col] = global END of segment
    float dv0 = (h0 > 0) ? rsqrtf((float)h0) : 0.0f;
    float dv1 = (h1 > 0) ? rsqrtf((float)h1) : 0.0f;
    sdv[t] = dv0; sdv[t + 256] = dv1;
    int col0 = g * CPG + t;
    int col1 = col0 + 256;
    if (col0 < GN) {
        rowptr[col0] = gb + s[t];
        dinv[col0] = dv0;
    }
    if (t + 256 < CPG && col1 < GN) {
        rowptr[col1] = gb + s[t + 256];
        dinv[col1] = dv1;
    }
    __syncthreads();
    hist[t] = s[t] - h0;             // exclusive -> running counters
    hist[t + 256] = s[t + 256] - h1;
    __syncthreads();
    for (int idx = t; idx < m; idx += 256) {
        unsigned u = bk[idx];
        int cl = u >> 17;
        int r  = (int)(u & 0x1FFFFu);
        int pos = gb + atomicAdd(&hist[cl], 1);
        csr[pos] = r << 7;           // byte offset into bf16 [GD] rows
    }
    // ---- Xs seeding: Xs[col] = bf16(dinv[col] * weight[col]) ----
    // (sdv written before the syncs above; dtype branch hoisted OUT of the
    //  loop — r13 lesson: no runtime dtype branch inside a hot loop.)
    int lo = g * CPG;
    int ncols = min(CPG, GN - lo);
    int tot = ncols << 6;
    int wbf = flags[0];
    size_t gbase = (size_t)lo << 6;
    if (wbf) {
        const unsigned short* wp = (const unsigned short*)w;
        for (int idx = 4 * t; idx < tot; idx += 1024) {
            float dv = sdv[idx >> 6];
            size_t base = gbase + (size_t)idx;
            uint2 wv = *(const uint2*)(wp + base);
            uint2 o;
            o.x = (bf16bits(dv * bf_hi(wv.x)) << 16) | bf16bits(dv * bf_lo(wv.x));
            o.y = (bf16bits(dv * bf_hi(wv.y)) << 16) | bf16bits(dv * bf_lo(wv.y));
            *(uint2*)(XS + base) = o;
        }
    } else {
        const float* wp = (const float*)w;
        for (int idx = 4 * t; idx < tot; idx += 1024) {
            float dv = sdv[idx >> 6];
            size_t base = gbase + (size_t)idx;
            float4 wv = *(const float4*)(wp + base);
            uint2 o;
            o.x = (bf16bits(dv * wv.y) << 16) | bf16bits(dv * wv.x);
            o.y = (bf16bits(dv * wv.w) << 16) | bf16bits(dv * wv.z);
            *(uint2*)(XS + base) = o;
        }
    }
}

// ---- one hop, gather form over PRE-SCALED buffer XS (XS[r]=dinv[r]*x[r]).
// x_new = dinv[c] * sum(XS[r]); store Y = dinv[c]*x_new for next hop;
// OUT += alpha[k]*x_new. Loop is an unweighted gather-sum: 8 VMEM/iter
// (4 csr + 4 X), validity via cheap 1/0 fma weights. csr entries are byte
// offsets -> X address is one 32-bit add off the SGPR base. ----
__global__ void gather_kernel(const __hip_bfloat16* __restrict__ XS,
                              __hip_bfloat16* __restrict__ Y,
                              __hip_bfloat16* __restrict__ OUT,
                              const int* __restrict__ rowptr, const int* __restrict__ csr,
                              const float* __restrict__ dinv,
                              const void* __restrict__ alpha, const int* __restrict__ flags,
                              int k, int store_y, int N) {
    int t = blockIdx.x * blockDim.x + threadIdx.x;
    int node = __builtin_amdgcn_readfirstlane(t >> 6);
    if (node >= N) return;
    int lane = t & 63;
    int h = lane >> 4;        // edge slot within a 4-edge step
    int i = lane & 15;        // dim-quad index (dims 4i..4i+3)
    // independent early loads (hidden under the edge loop)
    int beg = node ? rowptr[node - 1] : 0;   // rowptr[c] = segment end
    int end = rowptr[node];
    float dc = dinv[node];
    float a = ld_f(alpha, k, flags[0]);
    size_t obase = (size_t)node * GD + 4 * i;
    uint2 uo = *(const uint2*)(OUT + obase);  // OUT row prefetch
    const char* xb = (const char*)XS;
    unsigned ioff = 8u * (unsigned)i;
    int last = end - 1;
    float f0 = 0.0f, f1 = 0.0f, f2 = 0.0f, f3 = 0.0f;
    for (int j = beg; j < end; j += 16) {
        int i0 = j + 0 + h;  int i1 = j + 4 + h;
        int i2 = j + 8 + h;  int i3 = j + 12 + h;
        unsigned r0 = (unsigned)csr[min(i0, last)];
        unsigned r1 = (unsigned)csr[min(i1, last)];
        unsigned r2 = (unsigned)csr[min(i2, last)];
        unsigned r3 = (unsigned)csr[min(i3, last)];
        float w0 = (i0 < end) ? 1.0f : 0.0f;
        float w1 = (i1 < end) ? 1.0f : 0.0f;
        float w2 = (i2 < end) ? 1.0f : 0.0f;
        float w3 = (i3 < end) ? 1.0f : 0.0f;
        uint2 u0 = *(const uint2*)(xb + (r0 + ioff));
        uint2 u1 = *(const uint2*)(xb + (r1 + ioff));
        uint2 u2 = *(const uint2*)(xb + (r2 + ioff));
        uint2 u3 = *(const uint2*)(xb + (r3 + ioff));
        f0 = fmaf(w0, bf_lo(u0.x), f0); f1 = fmaf(w0, bf_hi(u0.x), f1);
        f2 = fmaf(w0, bf_lo(u0.y), f2); f3 = fmaf(w0, bf_hi(u0.y), f3);
        f0 = fmaf(w1, bf_lo(u1.x), f0); f1 = fmaf(w1, bf_hi(u1.x), f1);
        f2 = fmaf(w1, bf_lo(u1.y), f2); f3 = fmaf(w1, bf_hi(u1.y), f3);
        f0 = fmaf(w2, bf_lo(u2.x), f0); f1 = fmaf(w2, bf_hi(u2.x), f1);
        f2 = fmaf(w2, bf_lo(u2.y), f2); f3 = fmaf(w2, bf_hi(u2.y), f3);
        f0 = fmaf(w3, bf_lo(u3.x), f0); f1 = fmaf(w3, bf_hi(u3.x), f1);
        f2 = fmaf(w3, bf_lo(u3.y), f2); f3 = fmaf(w3, bf_hi(u3.y), f3);
    }
    // combine the 4 edge slots (disjoint edge subsets)
    f0 += __shfl_xor(f0, 16, 64); f0 += __shfl_xor(f0, 32, 64);
    f1 += __shfl_xor(f1, 16, 64); f1 += __shfl_xor(f1, 32, 64);
    f2 += __shfl_xor(f2, 16, 64); f2 += __shfl_xor(f2, 32, 64);
    f3 += __shfl_xor(f3, 16, 64); f3 += __shfl_xor(f3, 32, 64);
    f0 *= dc; f1 *= dc; f2 *= dc; f3 *= dc;   // f = x_new
    if (h == 0) {
        if (store_y) {
            // next-hop pre-scaled buffer: dinv[c] * x_new
            uint2 p;
            p.x = (bf16bits(dc * f1) << 16) | bf16bits(dc * f0);
            p.y = (bf16bits(dc * f3) << 16) | bf16bits(dc * f2);
            *(uint2*)(Y + obase) = p;
        }
        float o0 = fmaf(a, f0, bf_lo(uo.x));
        float o1 = fmaf(a, f1, bf_hi(uo.x));
        float o2 = fmaf(a, f2, bf_lo(uo.y));
        float o3 = fmaf(a, f3, bf_hi(uo.y));
        uint2 q;
        q.x = (bf16bits(o1) << 16) | bf16bits(o0);
        q.y = (bf16bits(o3) << 16) | bf16bits(o2);
        *(uint2*)(OUT + obase) = q;
    }
}

// ---- bf16-pair dot helper ----
__device__ __forceinline__ float dot2_bf16(unsigned ua, unsigned ub) {
    return fmaf(bf_lo(ua), bf_lo(ub), bf_hi(ua) * bf_hi(ub));
}

// ---- res[e] = dot(OUT[row[e]], OUT[col[e]]) — 4 threads/edge, 2x16B per row ----
__global__ void dot_kernel(const __hip_bfloat16* __restrict__ OUT,
                           const int* __restrict__ edge, const int* __restrict__ flags,
                           void* __restrict__ res, int E) {
    int t = blockIdx.x * blockDim.x + threadIdx.x;
    int e = t >> 2;
    int sub = t & 3;
    if (e >= E) return;
    int e64 = flags[1];
    int wbf = flags[0];
    int r = ld_row(edge, e, e64);
    int c = ld_col(edge, e, e64);
    float p = 0.0f;
    if ((unsigned)r < (unsigned)GN && (unsigned)c < (unsigned)GN) {
        const uint4* pa = (const uint4*)(OUT + (size_t)r * GD + sub * 16);
        const uint4* pb = (const uint4*)(OUT + (size_t)c * GD + sub * 16);
        uint4 a0 = pa[0], a1 = pa[1];
        uint4 b0 = pb[0], b1 = pb[1];
        p = ((dot2_bf16(a0.x, b0.x) + dot2_bf16(a0.y, b0.y)) +
             (dot2_bf16(a0.z, b0.z) + dot2_bf16(a0.w, b0.w))) +
            ((dot2_bf16(a1.x, b1.x) + dot2_bf16(a1.y, b1.y)) +
             (dot2_bf16(a1.z, b1.z) + dot2_bf16(a1.w, b1.w)));
    }
    p += __shfl_down(p, 2, 4);
    p += __shfl_down(p, 1, 4);
    if (sub == 0) {
        if (wbf) ((__hip_bfloat16*)res)[e] = __float2bfloat16(p);
        else     ((float*)res)[e] = p;
    }
}

extern "C" void kernel_launch(void* const* d_in, const int* in_sizes, int n_in,
                              void* d_out, int out_size, void* d_ws, size_t ws_size,
                              hipStream_t stream) {
    const int E = GE, N = GN, ND = GN * GD;

    const void* edge   = d_in[0];
    const void* weight = d_in[1];
    const void* alpha  = d_in[2];

    // Workspace layout (~51 MB total)
    char* ws = (char*)d_ws;
    int*      flags     = (int*)ws;      ws += 256;
    int*      gcount    = (int*)ws;      ws += 1024;
    float*    dinv      = (float*)ws;    ws += (((size_t)N * 4 + 255) / 256) * 256;
    int*      rowptr    = (int*)ws;      ws += (((size_t)N * 4 + 255) / 256) * 256;
    unsigned* bucket    = (unsigned*)ws; ws += (size_t)NG * CAP * 4;   // 6.3 MB
    int*      csr       = (int*)ws;      ws += (size_t)E * 4;          // 4.8 MB
    __hip_bfloat16* X   = (__hip_bfloat16*)ws; ws += (size_t)ND * 2;   // 12.8 MB
    __hip_bfloat16* Y   = (__hip_bfloat16*)ws; ws += (size_t)ND * 2;   // 12.8 MB
    __hip_bfloat16* OUT = (__hip_bfloat16*)ws; ws += (size_t)ND * 2;   // 12.8 MB

    const int B = 256;

    detect_kernel<<<1, 256, 0, stream>>>(weight, edge, flags, gcount);

    // fused: radix partition (blocks 0..255) + OUT init (remaining blocks)
    {
        const int chunk = (E + NG - 1) / NG;          // 4688
        const int initBlocks = (ND / 4 + B - 1) / B;  // 6250
        p1init_kernel<<<NG + initBlocks, B, 0, stream>>>(
            (const int*)edge, flags, gcount, bucket, E, chunk,
            weight, alpha, OUT, ND);
    }
    // p2 also seeds X := bf16(dinv * weight)  (the pre-scaled hop buffer)
    p2_kernel<<<NG, 256, 0, stream>>>(bucket, gcount, rowptr, dinv, csr,
                                      weight, flags, X);

    // 3 propagation hops over pre-scaled buffers
    const int ggrid = (int)(((size_t)N * 64 + B - 1) / B);
    gather_kernel<<<ggrid, B, 0, stream>>>(X, Y, OUT, rowptr, csr, dinv, alpha, flags, 1, 1, N);
    gather_kernel<<<ggrid, B, 0, stream>>>(Y, X, OUT, rowptr, csr, dinv, alpha, flags, 2, 1, N);
    gather_kernel<<<ggrid, B, 0, stream>>>(X, Y, OUT, rowptr, csr, dinv, alpha, flags, 3, 0, N);

    // per-edge link scores (4 threads/edge, 2x uint4 per row)
    dot_kernel<<<(int)(((size_t)E * 4 + B - 1) / B), B, 0, stream>>>(OUT, (const int*)edge, flags, d_out, E);
}

// Round 2
// 258.983 us; speedup vs baseline: 1.0746x; 1.0011x over previous
//
#include <hip/hip_runtime.h>
#include <hip/hip_bf16.h>

// Problem constants: N=100000 nodes, E=1200000 edges, D=64, K=3 hops.
#define GN 100000
#define GE 1200000
#define GD 64
#define NG 256                 // col groups
#define CPG 391                // cols per group (256*391 = 100096 >= GN)
#define CAP 6144               // bucket capacity per group (mean 4688, std 68)
#define PADCAP 12032           // per-group padded csr region (>= CAP + 15*391 = 12009)
#define ZROFF (GN << 7)        // byte offset of the zeroed sentinel row

// ws_size ~256 MB (observed). This layout uses ~59 MB.
//
// History (see git log): r11 radix-partition CSR build; r12 predicated
// 16-edge gather blocks; r13 REGRESSION: runtime dtype branch if-converted
// -> double FETCH (lesson: no runtime dtype branches in hot loops).
// r14 fused p1+init. r15 dinv-PRESCALE: hop buffers store dinv[c]*x so the
// hop loop is an unweighted gather-sum (no per-edge dinv loads); csr holds
// byte offsets; 278->259 us. r16 (this): CSR segments PADDED to 16 with a
// zero sentinel row -> predication (min/cmp/cndmask) deleted from the hop
// loop; 4 broadcast csr loads replaced by 1 coalesced load + 4 shfl;
// rowptr pair -> single int2 begend load; p2 drops the cross-group scan
// (fixed g*PADCAP regions).

// ---------------------------------------------------------------------------
// Runtime dtype detection. flags[0]=1 if weight/alpha bf16 else fp32.
// flags[1]=1 if edge_index int64 else int32.  Also zeroes gcount and the
// sentinel row GN of both hop buffers (re-poisoned every launch).
// ---------------------------------------------------------------------------
__global__ void detect_kernel(const void* __restrict__ w,
                              const void* __restrict__ edge,
                              int* __restrict__ flags, int* __restrict__ gcount,
                              __hip_bfloat16* __restrict__ X,
                              __hip_bfloat16* __restrict__ Y) {
    __shared__ int s_badw, s_edgenz;
    if (threadIdx.x == 0) { s_badw = 0; s_edgenz = 0; }
    gcount[threadIdx.x] = 0;
    if (threadIdx.x < 16) {
        uint2 z; z.x = 0u; z.y = 0u;
        *(uint2*)(X + (size_t)GN * GD + 4 * threadIdx.x) = z;
        *(uint2*)(Y + (size_t)GN * GD + 4 * threadIdx.x) = z;
    }
    __syncthreads();
    const unsigned short* wh = (const unsigned short*)w;
    const unsigned int*   ei = (const unsigned int*)edge;
    int badw = 0, edgenz = 0;
    for (int i = threadIdx.x; i < 4096; i += 256) {
        unsigned int bits = ((unsigned int)wh[i]) << 16;
        float v = __uint_as_float(bits);
        if (!(fabsf(v) <= 100.0f)) badw = 1;         // NaN/Inf/huge -> fp32 backing
        if ((i & 1) == 1 && ei[i] != 0u) edgenz = 1; // odd word nonzero -> int32
    }
    if (badw)   atomicOr(&s_badw, 1);
    if (edgenz) atomicOr(&s_edgenz, 1);
    __syncthreads();
    if (threadIdx.x == 0) {
        flags[0] = s_badw ? 0 : 1;
        flags[1] = s_edgenz ? 0 : 1;
    }
}

__device__ __forceinline__ int ld_row(const int* __restrict__ edge, int e, int e64) {
    return e64 ? edge[2 * (size_t)e] : edge[e];
}
__device__ __forceinline__ int ld_col(const int* __restrict__ edge, int e, int e64) {
    return e64 ? edge[2 * ((size_t)GE + (size_t)e)] : edge[(size_t)GE + (size_t)e];
}
__device__ __forceinline__ float ld_f(const void* __restrict__ p, size_t i, int bf16f) {
    if (bf16f) return __bfloat162float(((const __hip_bfloat16*)p)[i]);
    return ((const float*)p)[i];
}

__device__ __forceinline__ float bf_lo(unsigned u) { return __uint_as_float(u << 16); }
__device__ __forceinline__ float bf_hi(unsigned u) { return __uint_as_float(u & 0xFFFF0000u); }
__device__ __forceinline__ unsigned bf16bits(float f) {
    __hip_bfloat16 h = __float2bfloat16(f);
    unsigned short s;
    __builtin_memcpy(&s, &h, 2);
    return (unsigned)s;
}

// ---- fused P1 (blocks 0..NG-1) + OUT-init (remaining blocks) ----
// P1: partition edges into NG col-group buckets (packed (c_local<<17)|r).
// init: OUT = bf16(alpha[0] * weight). (X seeding in p2: Xs=dinv*w.)
__global__ void p1init_kernel(const int* __restrict__ edge, const int* __restrict__ flags,
                              int* __restrict__ gcount, unsigned* __restrict__ bucket,
                              int E, int chunk,
                              const void* __restrict__ w, const void* __restrict__ alpha,
                              __hip_bfloat16* __restrict__ OUT, int nd) {
    if (blockIdx.x < NG) {
        __shared__ int cnt[NG];
        __shared__ int base[NG];
        int t = threadIdx.x;
        int e64 = flags[1];
        cnt[t] = 0;
        __syncthreads();
        int lo = blockIdx.x * chunk;
        int hiE = min(lo + chunk, E);
        // pass A: count valid edges per group
        for (int e = lo + t; e < hiE; e += 256) {
            int c = ld_col(edge, e, e64);
            int r = ld_row(edge, e, e64);
            if ((unsigned)c < (unsigned)GN && (unsigned)r < (unsigned)GN)
                atomicAdd(&cnt[c / CPG], 1);
        }
        __syncthreads();
        int cv = cnt[t];
        base[t] = (cv > 0) ? atomicAdd(&gcount[t], cv) : 0;
        __syncthreads();
        cnt[t] = 0;   // reuse as running offsets
        __syncthreads();
        // pass B: write entries (chunk is L2-hot from pass A)
        for (int e = lo + t; e < hiE; e += 256) {
            int c = ld_col(edge, e, e64);
            int r = ld_row(edge, e, e64);
            if ((unsigned)c < (unsigned)GN && (unsigned)r < (unsigned)GN) {
                int g = c / CPG;
                int idx = base[g] + atomicAdd(&cnt[g], 1);
                if (idx < CAP)
                    bucket[(size_t)g * CAP + idx] = ((unsigned)(c - g * CPG) << 17) | (unsigned)r;
            }
        }
    } else {
        int bid = blockIdx.x - NG;
        int i = 4 * (bid * 256 + (int)threadIdx.x);
        int wbf = flags[0];
        if (i < nd) {
            float a0 = ld_f(alpha, 0, wbf);
            float v0 = ld_f(w, i + 0, wbf);
            float v1 = ld_f(w, i + 1, wbf);
            float v2 = ld_f(w, i + 2, wbf);
            float v3 = ld_f(w, i + 3, wbf);
            uint2 oq;
            oq.x = (bf16bits(a0 * v1) << 16) | bf16bits(a0 * v0);
            oq.y = (bf16bits(a0 * v3) << 16) | bf16bits(a0 * v2);
            *(uint2*)(OUT + i) = oq;
        }
    }
}

// ---- P2: per group, LDS hist -> dinv + begend + padded csr (byte offsets,
// segments padded to 16 with ZROFF sentinel) + Xs = bf16(dinv*w) seeding.
// Fixed per-group csr region [g*PADCAP, (g+1)*PADCAP) -> no cross-group scan.
__global__ void p2_kernel(const unsigned* __restrict__ bucket, const int* __restrict__ gcount,
                          int2* __restrict__ begend, float* __restrict__ dinv,
                          int* __restrict__ csr,
                          const void* __restrict__ w, const int* __restrict__ flags,
                          __hip_bfloat16* __restrict__ XS) {
    int g = blockIdx.x;
    int t = threadIdx.x;
    __shared__ int hist[512];
    __shared__ int s[512];
    __shared__ float sdv[512];
    hist[t] = 0; hist[t + 256] = 0;
    __syncthreads();
    int mg = gcount[g]; if (mg > CAP) mg = CAP;
    const unsigned* bk = bucket + (size_t)g * CAP;
    for (int idx = t; idx < mg; idx += 256)
        atomicAdd(&hist[bk[idx] >> 17], 1);
    __syncthreads();
    int h0 = hist[t], h1 = hist[t + 256];
    int p0 = (h0 + 15) & ~15;          // padded per-col counts
    int p1 = (h1 + 15) & ~15;
    s[t] = p0; s[t + 256] = p1;
    __syncthreads();
    for (int off = 1; off < 512; off <<= 1) {
        int v0 = (t >= off) ? s[t - off] : 0;
        int v1 = (t + 256 >= off) ? s[t + 256 - off] : 0;
        __syncthreads();
        s[t] += v0; s[t + 256] += v1;
        __syncthreads();
    }
    int gb = g * PADCAP;
    int beg0 = gb + s[t] - p0;          // exclusive padded base, absolute
    int beg1 = gb + s[t + 256] - p1;
    float dv0 = (h0 > 0) ? rsqrtf((float)h0) : 0.0f;   // dinv from REAL degree
    float dv1 = (h1 > 0) ? rsqrtf((float)h1) : 0.0f;
    sdv[t] = dv0; sdv[t + 256] = dv1;
    int col0 = g * CPG + t;
    int col1 = col0 + 256;
    if (col0 < GN) {
        begend[col0] = make_int2(beg0, beg0 + p0);
        dinv[col0] = dv0;
    }
    if (t + 256 < CPG && col1 < GN) {
        begend[col1] = make_int2(beg1, beg1 + p1);
        dinv[col1] = dv1;
    }
    __syncthreads();
    hist[t] = s[t] - p0;             // exclusive -> running counters (local)
    hist[t + 256] = s[t + 256] - p1;
    __syncthreads();
    for (int idx = t; idx < mg; idx += 256) {
        unsigned u = bk[idx];
        int cl = u >> 17;
        int r  = (int)(u & 0x1FFFFu);
        int pos = gb + atomicAdd(&hist[cl], 1);
        csr[pos] = r << 7;           // byte offset into bf16 [GD] rows
    }
    // pad fill: slots [beg+h, beg+p) are disjoint from real slots -> no sync
    if (col0 < GN)
        for (int q = h0; q < p0; ++q) csr[beg0 + q] = ZROFF;
    if (t + 256 < CPG && col1 < GN)
        for (int q = h1; q < p1; ++q) csr[beg1 + q] = ZROFF;
    // ---- Xs seeding: Xs[col] = bf16(dinv[col] * weight[col]) ----
    // (dtype branch hoisted OUT of the loop — r13 lesson.)
    int lo = g * CPG;
    int ncols = min(CPG, GN - lo);
    int tot = ncols << 6;
    int wbf = flags[0];
    size_t gbase = (size_t)lo << 6;
    if (wbf) {
        const unsigned short* wp = (const unsigned short*)w;
        for (int idx = 4 * t; idx < tot; idx += 1024) {
            float dv = sdv[idx >> 6];
            size_t base = gbase + (size_t)idx;
            uint2 wv = *(const uint2*)(wp + base);
            uint2 o;
            o.x = (bf16bits(dv * bf_hi(wv.x)) << 16) | bf16bits(dv * bf_lo(wv.x));
            o.y = (bf16bits(dv * bf_hi(wv.y)) << 16) | bf16bits(dv * bf_lo(wv.y));
            *(uint2*)(XS + base) = o;
        }
    } else {
        const float* wp = (const float*)w;
        for (int idx = 4 * t; idx < tot; idx += 1024) {
            float dv = sdv[idx >> 6];
            size_t base = gbase + (size_t)idx;
            float4 wv = *(const float4*)(wp + base);
            uint2 o;
            o.x = (bf16bits(dv * wv.y) << 16) | bf16bits(dv * wv.x);
            o.y = (bf16bits(dv * wv.w) << 16) | bf16bits(dv * wv.z);
            *(uint2*)(XS + base) = o;
        }
    }
}

// ---- one hop over PRE-SCALED buffer XS (XS[r]=dinv[r]*x[r]), padded csr.
// x_new = dinv[c] * sum(XS[r]); Y = dinv[c]*x_new; OUT += alpha[k]*x_new.
// Inner loop is branch-free: segments are padded to 16 with the zeroed
// sentinel row, so no predication. 5 VMEM/iter (1 coalesced csr + 4 X);
// row offsets broadcast to slots via shfl (DS, shorter chain than 4
// broadcast VMEM loads). csr entries are byte offsets. ----
__global__ void gather_kernel(const __hip_bfloat16* __restrict__ XS,
                              __hip_bfloat16* __restrict__ Y,
                              __hip_bfloat16* __restrict__ OUT,
                              const int2* __restrict__ begend, const int* __restrict__ csr,
                              const float* __restrict__ dinv,
                              const void* __restrict__ alpha, const int* __restrict__ flags,
                              int k, int store_y, int N) {
    int t = blockIdx.x * blockDim.x + threadIdx.x;
    int node = __builtin_amdgcn_readfirstlane(t >> 6);
    if (node >= N) return;
    int lane = t & 63;
    int h = lane >> 4;        // edge slot within a 16-edge step
    int i = lane & 15;        // dim-quad index (dims 4i..4i+3) AND csr lane
    // independent early loads (hidden under the edge loop)
    int2 be = begend[node];
    int beg = be.x, end = be.y;
    float dc = dinv[node];
    float a = ld_f(alpha, k, flags[0]);
    size_t obase = (size_t)node * GD + 4 * i;
    uint2 uo = *(const uint2*)(OUT + obase);  // OUT row prefetch
    const char* xb = (const char*)XS;
    unsigned ioff = 8u * (unsigned)i;
    float f0 = 0.0f, f1 = 0.0f, f2 = 0.0f, f3 = 0.0f;
    for (int j = beg; j < end; j += 16) {
        // one coalesced load covers all 16 positions of this step
        int rv = csr[j + i];
        unsigned r0 = (unsigned)__shfl(rv, h,      16);
        unsigned r1 = (unsigned)__shfl(rv, 4 + h,  16);
        unsigned r2 = (unsigned)__shfl(rv, 8 + h,  16);
        unsigned r3 = (unsigned)__shfl(rv, 12 + h, 16);
        uint2 u0 = *(const uint2*)(xb + (r0 + ioff));
        uint2 u1 = *(const uint2*)(xb + (r1 + ioff));
        uint2 u2 = *(const uint2*)(xb + (r2 + ioff));
        uint2 u3 = *(const uint2*)(xb + (r3 + ioff));
        f0 += bf_lo(u0.x); f1 += bf_hi(u0.x); f2 += bf_lo(u0.y); f3 += bf_hi(u0.y);
        f0 += bf_lo(u1.x); f1 += bf_hi(u1.x); f2 += bf_lo(u1.y); f3 += bf_hi(u1.y);
        f0 += bf_lo(u2.x); f1 += bf_hi(u2.x); f2 += bf_lo(u2.y); f3 += bf_hi(u2.y);
        f0 += bf_lo(u3.x); f1 += bf_hi(u3.x); f2 += bf_lo(u3.y); f3 += bf_hi(u3.y);
    }
    // combine the 4 edge slots (disjoint edge subsets)
    f0 += __shfl_xor(f0, 16, 64); f0 += __shfl_xor(f0, 32, 64);
    f1 += __shfl_xor(f1, 16, 64); f1 += __shfl_xor(f1, 32, 64);
    f2 += __shfl_xor(f2, 16, 64); f2 += __shfl_xor(f2, 32, 64);
    f3 += __shfl_xor(f3, 16, 64); f3 += __shfl_xor(f3, 32, 64);
    f0 *= dc; f1 *= dc; f2 *= dc; f3 *= dc;   // f = x_new
    if (h == 0) {
        if (store_y) {
            // next-hop pre-scaled buffer: dinv[c] * x_new
            uint2 p;
            p.x = (bf16bits(dc * f1) << 16) | bf16bits(dc * f0);
            p.y = (bf16bits(dc * f3) << 16) | bf16bits(dc * f2);
            *(uint2*)(Y + obase) = p;
        }
        float o0 = fmaf(a, f0, bf_lo(uo.x));
        float o1 = fmaf(a, f1, bf_hi(uo.x));
        float o2 = fmaf(a, f2, bf_lo(uo.y));
        float o3 = fmaf(a, f3, bf_hi(uo.y));
        uint2 q;
        q.x = (bf16bits(o1) << 16) | bf16bits(o0);
        q.y = (bf16bits(o3) << 16) | bf16bits(o2);
        *(uint2*)(OUT + obase) = q;
    }
}

// ---- bf16-pair dot helper ----
__device__ __forceinline__ float dot2_bf16(unsigned ua, unsigned ub) {
    return fmaf(bf_lo(ua), bf_lo(ub), bf_hi(ua) * bf_hi(ub));
}

// ---- res[e] = dot(OUT[row[e]], OUT[col[e]]) — 4 threads/edge, 2x16B per row ----
__global__ void dot_kernel(const __hip_bfloat16* __restrict__ OUT,
                           const int* __restrict__ edge, const int* __restrict__ flags,
                           void* __restrict__ res, int E) {
    int t = blockIdx.x * blockDim.x + threadIdx.x;
    int e = t >> 2;
    int sub = t & 3;
    if (e >= E) return;
    int e64 = flags[1];
    int wbf = flags[0];
    int r = ld_row(edge, e, e64);
    int c = ld_col(edge, e, e64);
    float p = 0.0f;
    if ((unsigned)r < (unsigned)GN && (unsigned)c < (unsigned)GN) {
        const uint4* pa = (const uint4*)(OUT + (size_t)r * GD + sub * 16);
        const uint4* pb = (const uint4*)(OUT + (size_t)c * GD + sub * 16);
        uint4 a0 = pa[0], a1 = pa[1];
        uint4 b0 = pb[0], b1 = pb[1];
        p = ((dot2_bf16(a0.x, b0.x) + dot2_bf16(a0.y, b0.y)) +
             (dot2_bf16(a0.z, b0.z) + dot2_bf16(a0.w, b0.w))) +
            ((dot2_bf16(a1.x, b1.x) + dot2_bf16(a1.y, b1.y)) +
             (dot2_bf16(a1.z, b1.z) + dot2_bf16(a1.w, b1.w)));
    }
    p += __shfl_down(p, 2, 4);
    p += __shfl_down(p, 1, 4);
    if (sub == 0) {
        if (wbf) ((__hip_bfloat16*)res)[e] = __float2bfloat16(p);
        else     ((float*)res)[e] = p;
    }
}

extern "C" void kernel_launch(void* const* d_in, const int* in_sizes, int n_in,
                              void* d_out, int out_size, void* d_ws, size_t ws_size,
                              hipStream_t stream) {
    const int E = GE, N = GN, ND = GN * GD;
    const int NDP = (GN + 1) * GD;                  // +1 sentinel row

    const void* edge   = d_in[0];
    const void* weight = d_in[1];
    const void* alpha  = d_in[2];

    // Workspace layout (~59 MB total)
    char* ws = (char*)d_ws;
    int*      flags     = (int*)ws;      ws += 256;
    int*      gcount    = (int*)ws;      ws += 1024;
    float*    dinv      = (float*)ws;    ws += (((size_t)N * 4 + 255) / 256) * 256;
    int2*     begend    = (int2*)ws;     ws += (((size_t)N * 8 + 255) / 256) * 256;
    unsigned* bucket    = (unsigned*)ws; ws += (size_t)NG * CAP * 4;     // 6.3 MB
    int*      csr       = (int*)ws;      ws += (size_t)NG * PADCAP * 4;  // 12.3 MB
    __hip_bfloat16* X   = (__hip_bfloat16*)ws; ws += (size_t)NDP * 2;    // 12.8 MB
    __hip_bfloat16* Y   = (__hip_bfloat16*)ws; ws += (size_t)NDP * 2;    // 12.8 MB
    __hip_bfloat16* OUT = (__hip_bfloat16*)ws; ws += (size_t)ND * 2;     // 12.8 MB

    const int B = 256;

    detect_kernel<<<1, 256, 0, stream>>>(weight, edge, flags, gcount, X, Y);

    // fused: radix partition (blocks 0..255) + OUT init (remaining blocks)
    {
        const int chunk = (E + NG - 1) / NG;          // 4688
        const int initBlocks = (ND / 4 + B - 1) / B;  // 6250
        p1init_kernel<<<NG + initBlocks, B, 0, stream>>>(
            (const int*)edge, flags, gcount, bucket, E, chunk,
            weight, alpha, OUT, ND);
    }
    // p2 builds padded csr + begend + dinv and seeds X := bf16(dinv * weight)
    p2_kernel<<<NG, 256, 0, stream>>>(bucket, gcount, begend, dinv, csr,
                                      weight, flags, X);

    // 3 propagation hops over pre-scaled buffers
    const int ggrid = (int)(((size_t)N * 64 + B - 1) / B);
    gather_kernel<<<ggrid, B, 0, stream>>>(X, Y, OUT, begend, csr, dinv, alpha, flags, 1, 1, N);
    gather_kernel<<<ggrid, B, 0, stream>>>(Y, X, OUT, begend, csr, dinv, alpha, flags, 2, 1, N);
    gather_kernel<<<ggrid, B, 0, stream>>>(X, Y, OUT, begend, csr, dinv, alpha, flags, 3, 0, N);

    // per-edge link scores (4 threads/edge, 2x uint4 per row)
    dot_kernel<<<(int)(((size_t)E * 4 + B - 1) / B), B, 0, stream>>>(OUT, (const int*)edge, flags, d_out, E);
}

// Round 3
// 245.317 us; speedup vs baseline: 1.1345x; 1.0557x over previous
//
#include <hip/hip_runtime.h>
#include <hip/hip_bf16.h>

// Problem constants: N=100000 nodes, E=1200000 edges, D=64, K=3 hops.
#define GN 100000
#define GE 1200000
#define GD 64
#define NG 256                 // col groups
#define CPG 391                // cols per group (256*391 = 100096 >= GN)
#define CAP 6144               // bucket capacity per group (mean 4688, std 68)
#define PADCAP 12032           // per-group padded csr region (>= CAP + 15*391 = 12009)
#define ZROFF (GN << 7)        // byte offset of the zeroed sentinel row

// ws_size ~256 MB (observed). This layout uses ~59 MB.
//
// History (see git log): r11 radix-partition CSR build; r12 predicated
// 16-edge gather blocks; r13 REGRESSION: runtime dtype branch if-converted
// -> double FETCH (lesson: no runtime dtype branches in hot loops).
// r14 fused p1+init. r15 dinv-PRESCALE (278->259). r16 padded branch-free
// csr + shfl-broadcast: FLAT at 259 -> loop body exonerated; cost is the
// per-node serial latency chain (begend->csr->X) + 25k-WG dispatch churn.
// r17 (this): PERSISTENT waves. gather: 2048 blocks, each wave owns ~12
// strided nodes, depth-1 pipeline prefetching next node's begend/dinv/OUT
// row AND first csr vector (first edge-step peeled). dot: 2048 blocks,
// 2-stage pipeline (indices +1 iter, OUT-row gathers +1 iter).

// ---------------------------------------------------------------------------
// Runtime dtype detection. flags[0]=1 if weight/alpha bf16 else fp32.
// flags[1]=1 if edge_index int64 else int32.  Also zeroes gcount and the
// sentinel row GN of both hop buffers (re-poisoned every launch).
// ---------------------------------------------------------------------------
__global__ void detect_kernel(const void* __restrict__ w,
                              const void* __restrict__ edge,
                              int* __restrict__ flags, int* __restrict__ gcount,
                              __hip_bfloat16* __restrict__ X,
                              __hip_bfloat16* __restrict__ Y) {
    __shared__ int s_badw, s_edgenz;
    if (threadIdx.x == 0) { s_badw = 0; s_edgenz = 0; }
    gcount[threadIdx.x] = 0;
    if (threadIdx.x < 16) {
        uint2 z; z.x = 0u; z.y = 0u;
        *(uint2*)(X + (size_t)GN * GD + 4 * threadIdx.x) = z;
        *(uint2*)(Y + (size_t)GN * GD + 4 * threadIdx.x) = z;
    }
    __syncthreads();
    const unsigned short* wh = (const unsigned short*)w;
    const unsigned int*   ei = (const unsigned int*)edge;
    int badw = 0, edgenz = 0;
    for (int i = threadIdx.x; i < 4096; i += 256) {
        unsigned int bits = ((unsigned int)wh[i]) << 16;
        float v = __uint_as_float(bits);
        if (!(fabsf(v) <= 100.0f)) badw = 1;         // NaN/Inf/huge -> fp32 backing
        if ((i & 1) == 1 && ei[i] != 0u) edgenz = 1; // odd word nonzero -> int32
    }
    if (badw)   atomicOr(&s_badw, 1);
    if (edgenz) atomicOr(&s_edgenz, 1);
    __syncthreads();
    if (threadIdx.x == 0) {
        flags[0] = s_badw ? 0 : 1;
        flags[1] = s_edgenz ? 0 : 1;
    }
}

__device__ __forceinline__ int ld_row(const int* __restrict__ edge, int e, int e64) {
    return e64 ? edge[2 * (size_t)e] : edge[e];
}
__device__ __forceinline__ int ld_col(const int* __restrict__ edge, int e, int e64) {
    return e64 ? edge[2 * ((size_t)GE + (size_t)e)] : edge[(size_t)GE + (size_t)e];
}
__device__ __forceinline__ float ld_f(const void* __restrict__ p, size_t i, int bf16f) {
    if (bf16f) return __bfloat162float(((const __hip_bfloat16*)p)[i]);
    return ((const float*)p)[i];
}

__device__ __forceinline__ float bf_lo(unsigned u) { return __uint_as_float(u << 16); }
__device__ __forceinline__ float bf_hi(unsigned u) { return __uint_as_float(u & 0xFFFF0000u); }
__device__ __forceinline__ unsigned bf16bits(float f) {
    __hip_bfloat16 h = __float2bfloat16(f);
    unsigned short s;
    __builtin_memcpy(&s, &h, 2);
    return (unsigned)s;
}

// ---- fused P1 (blocks 0..NG-1) + OUT-init (remaining blocks) ----
// P1: partition edges into NG col-group buckets (packed (c_local<<17)|r).
// init: OUT = bf16(alpha[0] * weight). (X seeding in p2: Xs=dinv*w.)
__global__ void p1init_kernel(const int* __restrict__ edge, const int* __restrict__ flags,
                              int* __restrict__ gcount, unsigned* __restrict__ bucket,
                              int E, int chunk,
                              const void* __restrict__ w, const void* __restrict__ alpha,
                              __hip_bfloat16* __restrict__ OUT, int nd) {
    if (blockIdx.x < NG) {
        __shared__ int cnt[NG];
        __shared__ int base[NG];
        int t = threadIdx.x;
        int e64 = flags[1];
        cnt[t] = 0;
        __syncthreads();
        int lo = blockIdx.x * chunk;
        int hiE = min(lo + chunk, E);
        // pass A: count valid edges per group
        for (int e = lo + t; e < hiE; e += 256) {
            int c = ld_col(edge, e, e64);
            int r = ld_row(edge, e, e64);
            if ((unsigned)c < (unsigned)GN && (unsigned)r < (unsigned)GN)
                atomicAdd(&cnt[c / CPG], 1);
        }
        __syncthreads();
        int cv = cnt[t];
        base[t] = (cv > 0) ? atomicAdd(&gcount[t], cv) : 0;
        __syncthreads();
        cnt[t] = 0;   // reuse as running offsets
        __syncthreads();
        // pass B: write entries (chunk is L2-hot from pass A)
        for (int e = lo + t; e < hiE; e += 256) {
            int c = ld_col(edge, e, e64);
            int r = ld_row(edge, e, e64);
            if ((unsigned)c < (unsigned)GN && (unsigned)r < (unsigned)GN) {
                int g = c / CPG;
                int idx = base[g] + atomicAdd(&cnt[g], 1);
                if (idx < CAP)
                    bucket[(size_t)g * CAP + idx] = ((unsigned)(c - g * CPG) << 17) | (unsigned)r;
            }
        }
    } else {
        int bid = blockIdx.x - NG;
        int i = 4 * (bid * 256 + (int)threadIdx.x);
        int wbf = flags[0];
        if (i < nd) {
            float a0 = ld_f(alpha, 0, wbf);
            float v0 = ld_f(w, i + 0, wbf);
            float v1 = ld_f(w, i + 1, wbf);
            float v2 = ld_f(w, i + 2, wbf);
            float v3 = ld_f(w, i + 3, wbf);
            uint2 oq;
            oq.x = (bf16bits(a0 * v1) << 16) | bf16bits(a0 * v0);
            oq.y = (bf16bits(a0 * v3) << 16) | bf16bits(a0 * v2);
            *(uint2*)(OUT + i) = oq;
        }
    }
}

// ---- P2: per group, LDS hist -> dinv + begend + padded csr (byte offsets,
// segments padded to 16 with ZROFF sentinel) + Xs = bf16(dinv*w) seeding.
// Fixed per-group csr region [g*PADCAP, (g+1)*PADCAP) -> no cross-group scan.
__global__ void p2_kernel(const unsigned* __restrict__ bucket, const int* __restrict__ gcount,
                          int2* __restrict__ begend, float* __restrict__ dinv,
                          int* __restrict__ csr,
                          const void* __restrict__ w, const int* __restrict__ flags,
                          __hip_bfloat16* __restrict__ XS) {
    int g = blockIdx.x;
    int t = threadIdx.x;
    __shared__ int hist[512];
    __shared__ int s[512];
    __shared__ float sdv[512];
    hist[t] = 0; hist[t + 256] = 0;
    __syncthreads();
    int mg = gcount[g]; if (mg > CAP) mg = CAP;
    const unsigned* bk = bucket + (size_t)g * CAP;
    for (int idx = t; idx < mg; idx += 256)
        atomicAdd(&hist[bk[idx] >> 17], 1);
    __syncthreads();
    int h0 = hist[t], h1 = hist[t + 256];
    int p0 = (h0 + 15) & ~15;          // padded per-col counts
    int p1 = (h1 + 15) & ~15;
    s[t] = p0; s[t + 256] = p1;
    __syncthreads();
    for (int off = 1; off < 512; off <<= 1) {
        int v0 = (t >= off) ? s[t - off] : 0;
        int v1 = (t + 256 >= off) ? s[t + 256 - off] : 0;
        __syncthreads();
        s[t] += v0; s[t + 256] += v1;
        __syncthreads();
    }
    int gb = g * PADCAP;
    int beg0 = gb + s[t] - p0;          // exclusive padded base, absolute
    int beg1 = gb + s[t + 256] - p1;
    float dv0 = (h0 > 0) ? rsqrtf((float)h0) : 0.0f;   // dinv from REAL degree
    float dv1 = (h1 > 0) ? rsqrtf((float)h1) : 0.0f;
    sdv[t] = dv0; sdv[t + 256] = dv1;
    int col0 = g * CPG + t;
    int col1 = col0 + 256;
    if (col0 < GN) {
        begend[col0] = make_int2(beg0, beg0 + p0);
        dinv[col0] = dv0;
    }
    if (t + 256 < CPG && col1 < GN) {
        begend[col1] = make_int2(beg1, beg1 + p1);
        dinv[col1] = dv1;
    }
    __syncthreads();
    hist[t] = s[t] - p0;             // exclusive -> running counters (local)
    hist[t + 256] = s[t + 256] - p1;
    __syncthreads();
    for (int idx = t; idx < mg; idx += 256) {
        unsigned u = bk[idx];
        int cl = u >> 17;
        int r  = (int)(u & 0x1FFFFu);
        int pos = gb + atomicAdd(&hist[cl], 1);
        csr[pos] = r << 7;           // byte offset into bf16 [GD] rows
    }
    // pad fill: slots [beg+h, beg+p) are disjoint from real slots -> no sync
    if (col0 < GN)
        for (int q = h0; q < p0; ++q) csr[beg0 + q] = ZROFF;
    if (t + 256 < CPG && col1 < GN)
        for (int q = h1; q < p1; ++q) csr[beg1 + q] = ZROFF;
    // ---- Xs seeding: Xs[col] = bf16(dinv[col] * weight[col]) ----
    // (dtype branch hoisted OUT of the loop — r13 lesson.)
    int lo = g * CPG;
    int ncols = min(CPG, GN - lo);
    int tot = ncols << 6;
    int wbf = flags[0];
    size_t gbase = (size_t)lo << 6;
    if (wbf) {
        const unsigned short* wp = (const unsigned short*)w;
        for (int idx = 4 * t; idx < tot; idx += 1024) {
            float dv = sdv[idx >> 6];
            size_t base = gbase + (size_t)idx;
            uint2 wv = *(const uint2*)(wp + base);
            uint2 o;
            o.x = (bf16bits(dv * bf_hi(wv.x)) << 16) | bf16bits(dv * bf_lo(wv.x));
            o.y = (bf16bits(dv * bf_hi(wv.y)) << 16) | bf16bits(dv * bf_lo(wv.y));
            *(uint2*)(XS + base) = o;
        }
    } else {
        const float* wp = (const float*)w;
        for (int idx = 4 * t; idx < tot; idx += 1024) {
            float dv = sdv[idx >> 6];
            size_t base = gbase + (size_t)idx;
            float4 wv = *(const float4*)(wp + base);
            uint2 o;
            o.x = (bf16bits(dv * wv.y) << 16) | bf16bits(dv * wv.x);
            o.y = (bf16bits(dv * wv.w) << 16) | bf16bits(dv * wv.z);
            *(uint2*)(XS + base) = o;
        }
    }
}

// ---- 16-edge accumulate step (branch-free; pads hit the zero sentinel) ----
__device__ __forceinline__ void acc16(int rv, unsigned ioff, const char* __restrict__ xb,
                                      int h, float& f0, float& f1, float& f2, float& f3) {
    unsigned r0 = (unsigned)__shfl(rv, h,      16);
    unsigned r1 = (unsigned)__shfl(rv, 4 + h,  16);
    unsigned r2 = (unsigned)__shfl(rv, 8 + h,  16);
    unsigned r3 = (unsigned)__shfl(rv, 12 + h, 16);
    uint2 u0 = *(const uint2*)(xb + (r0 + ioff));
    uint2 u1 = *(const uint2*)(xb + (r1 + ioff));
    uint2 u2 = *(const uint2*)(xb + (r2 + ioff));
    uint2 u3 = *(const uint2*)(xb + (r3 + ioff));
    f0 += bf_lo(u0.x); f1 += bf_hi(u0.x); f2 += bf_lo(u0.y); f3 += bf_hi(u0.y);
    f0 += bf_lo(u1.x); f1 += bf_hi(u1.x); f2 += bf_lo(u1.y); f3 += bf_hi(u1.y);
    f0 += bf_lo(u2.x); f1 += bf_hi(u2.x); f2 += bf_lo(u2.y); f3 += bf_hi(u2.y);
    f0 += bf_lo(u3.x); f1 += bf_hi(u3.x); f2 += bf_lo(u3.y); f3 += bf_hi(u3.y);
}

// ---- one hop over PRE-SCALED buffer XS (XS[r]=dinv[r]*x[r]), padded csr.
// PERSISTENT: 8192 waves, each owns nodes wid, wid+W, ... Depth-1 node
// pipeline: next node's begend/dinv/OUT row + FIRST csr vector prefetched
// while the current node computes (first edge-step peeled to consume it).
__global__ void gather_kernel(const __hip_bfloat16* __restrict__ XS,
                              __hip_bfloat16* __restrict__ Y,
                              __hip_bfloat16* __restrict__ OUT,
                              const int2* __restrict__ begend, const int* __restrict__ csr,
                              const float* __restrict__ dinv,
                              const void* __restrict__ alpha, const int* __restrict__ flags,
                              int k, int store_y, int N, int W) {
    int t = blockIdx.x * blockDim.x + threadIdx.x;
    int wid = __builtin_amdgcn_readfirstlane(t >> 6);
    if (wid >= N) return;
    int lane = t & 63;
    int h = lane >> 4;        // edge slot within a 16-edge step
    int i = lane & 15;        // dim-quad index (dims 4i..4i+3) AND csr lane
    float a = ld_f(alpha, k, flags[0]);
    const char* xb = (const char*)XS;
    unsigned ioff = 8u * (unsigned)i;
    // prologue: node 0 of this wave
    int node = wid;
    int2 be = begend[node];
    float dc = dinv[node];
    size_t obase = (size_t)node * GD + 4 * i;
    uint2 uo = *(const uint2*)(OUT + obase);  // OUT row prefetch
    int rv = csr[be.x + i];                   // first-step csr prefetch
    for (;;) {
        int nn = node + W;
        bool more = nn < N;
        int2 be_n = make_int2(0, 0);
        float dc_n = 0.0f;
        uint2 uo_n; uo_n.x = 0u; uo_n.y = 0u;
        int rv_n = 0;
        if (more) {   // issue next node's independent loads early
            be_n = begend[nn];
            dc_n = dinv[nn];
            uo_n = *(const uint2*)(OUT + (size_t)nn * GD + 4 * i);
        }
        float f0 = 0.0f, f1 = 0.0f, f2 = 0.0f, f3 = 0.0f;
        int j = be.x;
        if (j < be.y) {
            acc16(rv, ioff, xb, h, f0, f1, f2, f3);      // peeled: uses prefetch
            for (j += 16; j < be.y; j += 16)
                acc16(csr[j + i], ioff, xb, h, f0, f1, f2, f3);
        }
        if (more) rv_n = csr[be_n.x + i];    // next node's first csr vector
        // combine the 4 edge slots (disjoint edge subsets)
        f0 += __shfl_xor(f0, 16, 64); f0 += __shfl_xor(f0, 32, 64);
        f1 += __shfl_xor(f1, 16, 64); f1 += __shfl_xor(f1, 32, 64);
        f2 += __shfl_xor(f2, 16, 64); f2 += __shfl_xor(f2, 32, 64);
        f3 += __shfl_xor(f3, 16, 64); f3 += __shfl_xor(f3, 32, 64);
        f0 *= dc; f1 *= dc; f2 *= dc; f3 *= dc;   // f = x_new
        if (h == 0) {
            if (store_y) {
                // next-hop pre-scaled buffer: dinv[c] * x_new
                uint2 p;
                p.x = (bf16bits(dc * f1) << 16) | bf16bits(dc * f0);
                p.y = (bf16bits(dc * f3) << 16) | bf16bits(dc * f2);
                *(uint2*)(Y + obase) = p;
            }
            float o0 = fmaf(a, f0, bf_lo(uo.x));
            float o1 = fmaf(a, f1, bf_hi(uo.x));
            float o2 = fmaf(a, f2, bf_lo(uo.y));
            float o3 = fmaf(a, f3, bf_hi(uo.y));
            uint2 q;
            q.x = (bf16bits(o1) << 16) | bf16bits(o0);
            q.y = (bf16bits(o3) << 16) | bf16bits(o2);
            *(uint2*)(OUT + obase) = q;
        }
        if (!more) break;
        node = nn; be = be_n; dc = dc_n; uo = uo_n; rv = rv_n;
        obase = (size_t)node * GD + 4 * i;
    }
}

// ---- bf16-pair dot helper ----
__device__ __forceinline__ float dot2_bf16(unsigned ua, unsigned ub) {
    return fmaf(bf_lo(ua), bf_lo(ub), bf_hi(ua) * bf_hi(ub));
}

// ---- res[e] = dot(OUT[row[e]], OUT[col[e]]) — 4 threads/edge, persistent
// quads with a 2-stage pipeline: indices one iteration ahead, OUT-row
// gathers one iteration ahead (rows consumed a full iteration after issue).
__global__ void dot_kernel(const __hip_bfloat16* __restrict__ OUT,
                           const int* __restrict__ edge, const int* __restrict__ flags,
                           void* __restrict__ res, int E, int NQ) {
    int t = blockIdx.x * blockDim.x + threadIdx.x;
    int q = t >> 2;
    int sub = t & 3;
    if (q >= E) return;
    int e64 = flags[1];
    int wbf = flags[0];
    // prologue: edge e0 indices + rows
    int e0 = q;
    int r0 = ld_row(edge, e0, e64);
    int c0 = ld_col(edge, e0, e64);
    float m0 = ((unsigned)r0 < (unsigned)GN && (unsigned)c0 < (unsigned)GN) ? 1.0f : 0.0f;
    unsigned rc = ((unsigned)r0 < (unsigned)GN) ? (unsigned)r0 : 0u;
    unsigned cc = ((unsigned)c0 < (unsigned)GN) ? (unsigned)c0 : 0u;
    const uint4* pa = (const uint4*)(OUT + (size_t)rc * GD + sub * 16);
    const uint4* pb = (const uint4*)(OUT + (size_t)cc * GD + sub * 16);
    uint4 a0 = pa[0], a1 = pa[1], b0 = pb[0], b1 = pb[1];
    int e1 = e0 + NQ;
    bool more1 = e1 < E;
    int r1 = 0, c1 = 0;
    if (more1) { r1 = ld_row(edge, e1, e64); c1 = ld_col(edge, e1, e64); }
    for (;;) {
        // stage: issue NEXT edge's row gathers (indices arrived last iter)
        uint4 na0, na1, nb0, nb1;
        na0.x=na0.y=na0.z=na0.w=0u; na1=na0; nb0=na0; nb1=na0;
        float m1 = 0.0f;
        if (more1) {
            m1 = ((unsigned)r1 < (unsigned)GN && (unsigned)c1 < (unsigned)GN) ? 1.0f : 0.0f;
            unsigned rc1 = ((unsigned)r1 < (unsigned)GN) ? (unsigned)r1 : 0u;
            unsigned cc1 = ((unsigned)c1 < (unsigned)GN) ? (unsigned)c1 : 0u;
            const uint4* qa = (const uint4*)(OUT + (size_t)rc1 * GD + sub * 16);
            const uint4* qb = (const uint4*)(OUT + (size_t)cc1 * GD + sub * 16);
            na0 = qa[0]; na1 = qa[1]; nb0 = qb[0]; nb1 = qb[1];
        }
        // stage: issue indices two ahead
        int e2 = e1 + NQ;
        bool more2 = more1 && (e2 < E);
        int r2 = 0, c2 = 0;
        if (more2) { r2 = ld_row(edge, e2, e64); c2 = ld_col(edge, e2, e64); }
        // compute current edge (rows issued one full iteration ago)
        float p = (((dot2_bf16(a0.x, b0.x) + dot2_bf16(a0.y, b0.y)) +
                    (dot2_bf16(a0.z, b0.z) + dot2_bf16(a0.w, b0.w))) +
                   ((dot2_bf16(a1.x, b1.x) + dot2_bf16(a1.y, b1.y)) +
                    (dot2_bf16(a1.z, b1.z) + dot2_bf16(a1.w, b1.w)))) * m0;
        p += __shfl_down(p, 2, 4);
        p += __shfl_down(p, 1, 4);
        if (sub == 0) {
            if (wbf) ((__hip_bfloat16*)res)[e0] = __float2bfloat16(p);
            else     ((float*)res)[e0] = p;
        }
        if (!more1) break;
        e0 = e1; m0 = m1;
        a0 = na0; a1 = na1; b0 = nb0; b1 = nb1;
        e1 = e2; more1 = more2; r1 = r2; c1 = c2;
    }
}

extern "C" void kernel_launch(void* const* d_in, const int* in_sizes, int n_in,
                              void* d_out, int out_size, void* d_ws, size_t ws_size,
                              hipStream_t stream) {
    const int E = GE, N = GN, ND = GN * GD;
    const int NDP = (GN + 1) * GD;                  // +1 sentinel row

    const void* edge   = d_in[0];
    const void* weight = d_in[1];
    const void* alpha  = d_in[2];

    // Workspace layout (~59 MB total)
    char* ws = (char*)d_ws;
    int*      flags     = (int*)ws;      ws += 256;
    int*      gcount    = (int*)ws;      ws += 1024;
    float*    dinv      = (float*)ws;    ws += (((size_t)N * 4 + 255) / 256) * 256;
    int2*     begend    = (int2*)ws;     ws += (((size_t)N * 8 + 255) / 256) * 256;
    unsigned* bucket    = (unsigned*)ws; ws += (size_t)NG * CAP * 4;     // 6.3 MB
    int*      csr       = (int*)ws;      ws += (size_t)NG * PADCAP * 4;  // 12.3 MB
    __hip_bfloat16* X   = (__hip_bfloat16*)ws; ws += (size_t)NDP * 2;    // 12.8 MB
    __hip_bfloat16* Y   = (__hip_bfloat16*)ws; ws += (size_t)NDP * 2;    // 12.8 MB
    __hip_bfloat16* OUT = (__hip_bfloat16*)ws; ws += (size_t)ND * 2;     // 12.8 MB

    const int B = 256;

    detect_kernel<<<1, 256, 0, stream>>>(weight, edge, flags, gcount, X, Y);

    // fused: radix partition (blocks 0..255) + OUT init (remaining blocks)
    {
        const int chunk = (E + NG - 1) / NG;          // 4688
        const int initBlocks = (ND / 4 + B - 1) / B;  // 6250
        p1init_kernel<<<NG + initBlocks, B, 0, stream>>>(
            (const int*)edge, flags, gcount, bucket, E, chunk,
            weight, alpha, OUT, ND);
    }
    // p2 builds padded csr + begend + dinv and seeds X := bf16(dinv * weight)
    p2_kernel<<<NG, 256, 0, stream>>>(bucket, gcount, begend, dinv, csr,
                                      weight, flags, X);

    // 3 propagation hops, persistent waves (8192 waves, ~12 nodes each)
    const int PB = 2048;                 // 8 blocks/CU
    const int W  = PB * (B / 64);        // 8192 waves
    gather_kernel<<<PB, B, 0, stream>>>(X, Y, OUT, begend, csr, dinv, alpha, flags, 1, 1, N, W);
    gather_kernel<<<PB, B, 0, stream>>>(Y, X, OUT, begend, csr, dinv, alpha, flags, 2, 1, N, W);
    gather_kernel<<<PB, B, 0, stream>>>(X, Y, OUT, begend, csr, dinv, alpha, flags, 3, 0, N, W);

    // per-edge link scores, persistent 2-stage pipelined quads
    const int NQ = PB * B / 4;           // 131072 quads
    dot_kernel<<<PB, B, 0, stream>>>(OUT, (const int*)edge, flags, d_out, E, NQ);
}